// Round 1
// baseline (110.428 us; speedup 1.0000x reference)
//
#include <hip/hip_runtime.h>
#include <hip/hip_bf16.h>

#define BSZ   4
#define NTOK  1024
#define DIN   384
#define DST   16
#define MROWS (BSZ * NTOK)   // 4096
#define NCOLS 800            // 384 (dts) + 384 (dtd) + 16 (B) + 16 (C)
#define KDIM  384

__device__ __forceinline__ float softplus_f(float z) {
  return (z > 20.0f) ? z : log1pf(expf(z));
}

__device__ __forceinline__ unsigned short f32_to_bf16(float f) {
  unsigned int u = __float_as_uint(f);
  unsigned int rnd = 0x7fffu + ((u >> 16) & 1u);   // round-to-nearest-even
  return (unsigned short)((u + rnd) >> 16);
}

// ---------------------------------------------------------------------------
// Kernel 1: fused projection GEMM  out[r, c] = dot(x[r, :], Wcat[c, :])
//   c in [0,384)   : delta_s = min(softplus(.+b_dts), 0.15) -> bf16, low u16 of d_out dword
//   c in [384,768) : delta_d = min(softplus(.+b_dtd), 0.15) -> bf16, high u16
//   c in [768,784) : B_mat (f32) -> ws
//   c in [784,800) : C_mat (f32) -> ws
// ---------------------------------------------------------------------------
__global__ __launch_bounds__(256) void proj_kernel(
    const float* __restrict__ x,
    const float* __restrict__ Wdts, const float* __restrict__ bdts,
    const float* __restrict__ Wdtd, const float* __restrict__ bdtd,
    const float* __restrict__ WB,   const float* __restrict__ WC,
    unsigned short* __restrict__ dpack,   // d_out viewed as u16[MROWS*DIN*2]
    float* __restrict__ Bmat, float* __restrict__ Cmat)
{
  __shared__ float As[32][68];   // [k][m], stride 68 keeps float4 align + low conflicts
  __shared__ float Bs[32][68];   // [k][c]
  const int t    = threadIdx.x;
  const int bm   = blockIdx.x & 63;   // 64 row tiles
  const int bn   = blockIdx.x >> 6;   // 13 col tiles
  const int row0 = bm * 64, col0 = bn * 64;
  const int tx = t & 15, ty = t >> 4;
  const int lr = t >> 3;              // 0..31 loader row
  const int lk = (t & 7) * 4;         // 0..28 loader k (float4)

  float acc[4][4] = {{0.f, 0.f, 0.f, 0.f}, {0.f, 0.f, 0.f, 0.f},
                     {0.f, 0.f, 0.f, 0.f}, {0.f, 0.f, 0.f, 0.f}};

  for (int k0 = 0; k0 < KDIM; k0 += 32) {
#pragma unroll
    for (int h = 0; h < 2; ++h) {
      int r = lr + h * 32;
      float4 v = *(const float4*)&x[(long)(row0 + r) * KDIM + k0 + lk];
      As[lk + 0][r] = v.x; As[lk + 1][r] = v.y; As[lk + 2][r] = v.z; As[lk + 3][r] = v.w;
    }
#pragma unroll
    for (int h = 0; h < 2; ++h) {
      int cc = lr + h * 32;
      int c  = col0 + cc;
      float4 v = make_float4(0.f, 0.f, 0.f, 0.f);
      if (c < NCOLS) {
        const float* wrow;
        if (c < 384)      wrow = Wdts + (long)c * KDIM;
        else if (c < 768) wrow = Wdtd + (long)(c - 384) * KDIM;
        else if (c < 784) wrow = WB   + (long)(c - 768) * KDIM;
        else              wrow = WC   + (long)(c - 784) * KDIM;
        v = *(const float4*)&wrow[k0 + lk];
      }
      Bs[lk + 0][cc] = v.x; Bs[lk + 1][cc] = v.y; Bs[lk + 2][cc] = v.z; Bs[lk + 3][cc] = v.w;
    }
    __syncthreads();
#pragma unroll
    for (int k = 0; k < 32; ++k) {
      float4 a  = *(const float4*)&As[k][ty * 4];
      float4 bb = *(const float4*)&Bs[k][tx * 4];
      float av[4] = {a.x, a.y, a.z, a.w};
      float bv[4] = {bb.x, bb.y, bb.z, bb.w};
#pragma unroll
      for (int i = 0; i < 4; ++i)
#pragma unroll
        for (int jj = 0; jj < 4; ++jj)
          acc[i][jj] = fmaf(av[i], bv[jj], acc[i][jj]);
    }
    __syncthreads();
  }

#pragma unroll
  for (int i = 0; i < 4; ++i) {
    int r = row0 + ty * 4 + i;
#pragma unroll
    for (int jj = 0; jj < 4; ++jj) {
      int c = col0 + tx * 4 + jj;
      float v = acc[i][jj];
      if (c < 384) {
        float dsv = fminf(softplus_f(v + bdts[c]), 0.15f);
        dpack[((long)r * DIN + c) * 2 + 0] = f32_to_bf16(dsv);
      } else if (c < 768) {
        int dd = c - 384;
        float ddv = fminf(softplus_f(v + bdtd[dd]), 0.15f);
        dpack[((long)r * DIN + dd) * 2 + 1] = f32_to_bf16(ddv);
      } else if (c < 784) {
        Bmat[(long)r * DST + (c - 768)] = v;
      } else if (c < NCOLS) {
        Cmat[(long)r * DST + (c - 784)] = v;
      }
    }
  }
}

// ---------------------------------------------------------------------------
// Kernel 2: per-(b,d) reaction-diffusion recurrence over the 32x32 grid x 16 states.
//   block = (b, d); thread owns rows n = t, t+256, t+512, t+768 (all 16 s each).
//   h center + h0 in registers; h mirrored in LDS (stride 20 floats / row).
//   Reads packed bf16 deltas from d_out (column-exclusive), writes y over them.
// ---------------------------------------------------------------------------
__global__ __launch_bounds__(256) void ssm_kernel(
    const float* __restrict__ x,
    const float* __restrict__ Bmat,
    const float* __restrict__ Cmat,
    const float* __restrict__ Dparam,
    const float* __restrict__ Alog,
    const float* __restrict__ diffraw,
    const int*   __restrict__ Kp,
    float* out)   // d_out: holds packed deltas on entry, y on exit (no __restrict__)
{
  __shared__ float hl[NTOK * 20];   // 81920 B
  const int t   = threadIdx.x;
  const int d   = blockIdx.x % DIN;
  const int b   = blockIdx.x / DIN;
  const int K   = Kp[0];
  const float dt = 1.0f / (float)K;
  const float Dc = 0.5f / (1.0f + expf(-diffraw[d]));   // sigmoid * 0.5

  float A_s[16];
#pragma unroll
  for (int s = 0; s < 16; ++s)
    A_s[s] = -log1pf(expf(Alog[d * DST + s]));          // -softplus(A_log)

  float h0r[4][16], hreg[4][16];
  float a1[4], a2[4], xv[4];
  const unsigned int* dpk = (const unsigned int*)out;

#pragma unroll
  for (int j = 0; j < 4; ++j) {
    int n = t + j * 256;
    long base = (long)(b * NTOK + n);
    xv[j] = x[base * DIN + d];
    unsigned int pk = dpk[base * DIN + d];
    float dsv = __uint_as_float(pk << 16);
    float ddv = __uint_as_float(pk & 0xffff0000u);
    a1[j] = dt * dsv;
    a2[j] = dt * ddv * Dc;
    const float4* Bp = (const float4*)(Bmat + base * DST);
#pragma unroll
    for (int q = 0; q < 4; ++q) {
      float4 bv = Bp[q];
      h0r[j][q * 4 + 0] = xv[j] * bv.x;
      h0r[j][q * 4 + 1] = xv[j] * bv.y;
      h0r[j][q * 4 + 2] = xv[j] * bv.z;
      h0r[j][q * 4 + 3] = xv[j] * bv.w;
    }
#pragma unroll
    for (int s = 0; s < 16; ++s) hreg[j][s] = h0r[j][s];
#pragma unroll
    for (int q = 0; q < 4; ++q)
      *(float4*)&hl[n * 20 + q * 4] =
          make_float4(hreg[j][q * 4 + 0], hreg[j][q * 4 + 1],
                      hreg[j][q * 4 + 2], hreg[j][q * 4 + 3]);
  }
  __syncthreads();

  for (int k = 0; k < K; ++k) {
#pragma unroll
    for (int j = 0; j < 4; ++j) {
      int n = t + j * 256;
      int r = n >> 5, c = n & 31;
      int nu = (r > 0)  ? n - 32 : n;   // replicate padding = clamped index
      int nd = (r < 31) ? n + 32 : n;
      int nl = (c > 0)  ? n - 1  : n;
      int nr = (c < 31) ? n + 1  : n;
      const float* pu = &hl[nu * 20];
      const float* pd = &hl[nd * 20];
      const float* pl = &hl[nl * 20];
      const float* pr = &hl[nr * 20];
#pragma unroll
      for (int q = 0; q < 4; ++q) {
        float4 u4 = *(const float4*)(pu + q * 4);
        float4 d4 = *(const float4*)(pd + q * 4);
        float4 l4 = *(const float4*)(pl + q * 4);
        float4 r4 = *(const float4*)(pr + q * 4);
        float uu[4] = {u4.x, u4.y, u4.z, u4.w};
        float dd[4] = {d4.x, d4.y, d4.z, d4.w};
        float ll[4] = {l4.x, l4.y, l4.z, l4.w};
        float rr[4] = {r4.x, r4.y, r4.z, r4.w};
#pragma unroll
        for (int e = 0; e < 4; ++e) {
          int s = q * 4 + e;
          float ce  = hreg[j][s];
          float lap = uu[e] + dd[e] + ll[e] + rr[e] - 4.0f * ce;
          float t1  = fmaf(A_s[s], ce, h0r[j][s]);   // A*h + h0
          float hv  = fmaf(a1[j], t1, ce);           // h + dt*ds*(A*h+h0)
          hv        = fmaf(a2[j], lap, hv);          // + dt*dd*Dc*lap
          hreg[j][s] = hv;
        }
      }
    }
    if (k + 1 < K) {
      __syncthreads();   // all reads of h_k done before overwrite
#pragma unroll
      for (int j = 0; j < 4; ++j) {
        int n = t + j * 256;
#pragma unroll
        for (int q = 0; q < 4; ++q)
          *(float4*)&hl[n * 20 + q * 4] =
              make_float4(hreg[j][q * 4 + 0], hreg[j][q * 4 + 1],
                          hreg[j][q * 4 + 2], hreg[j][q * 4 + 3]);
      }
      __syncthreads();
    }
  }

  const float Dp = Dparam[d];
#pragma unroll
  for (int j = 0; j < 4; ++j) {
    int n = t + j * 256;
    long base = (long)(b * NTOK + n);
    const float4* Cp = (const float4*)(Cmat + base * DST);
    float acc = 0.f;
#pragma unroll
    for (int q = 0; q < 4; ++q) {
      float4 cv = Cp[q];
      acc += hreg[j][q * 4 + 0] * cv.x + hreg[j][q * 4 + 1] * cv.y +
             hreg[j][q * 4 + 2] * cv.z + hreg[j][q * 4 + 3] * cv.w;
    }
    out[base * DIN + d] = acc + xv[j] * Dp;
  }
}

extern "C" void kernel_launch(void* const* d_in, const int* in_sizes, int n_in,
                              void* d_out, int out_size, void* d_ws, size_t ws_size,
                              hipStream_t stream) {
  const float* x     = (const float*)d_in[0];
  const float* Wdts  = (const float*)d_in[1];
  const float* bdts  = (const float*)d_in[2];
  const float* Wdtd  = (const float*)d_in[3];
  const float* bdtd  = (const float*)d_in[4];
  const float* WB    = (const float*)d_in[5];
  const float* WC    = (const float*)d_in[6];
  const float* Dpar  = (const float*)d_in[7];
  const float* Alog  = (const float*)d_in[8];
  const float* diffr = (const float*)d_in[9];
  const int*   Kst   = (const int*)d_in[10];

  float* out  = (float*)d_out;
  float* Bmat = (float*)d_ws;                    // 4096*16 f32
  float* Cmat = Bmat + (long)MROWS * DST;        // 4096*16 f32 (total ws use: 512 KB)

  proj_kernel<<<dim3(64 * 13), dim3(256), 0, stream>>>(
      x, Wdts, bdts, Wdtd, bdtd, WB, WC,
      (unsigned short*)d_out, Bmat, Cmat);

  ssm_kernel<<<dim3(BSZ * DIN), dim3(256), 0, stream>>>(
      x, Bmat, Cmat, Dpar, Alog, diffr, Kst, out);
}